// Round 6
// baseline (381.285 us; speedup 1.0000x reference)
//
#include <hip/hip_runtime.h>
#include <math.h>

#define HH 240
#define WW 240
#define PP (HH * WW)
#define PW 242              // padded width/height for NHWC bf16 conv input
#define LOG_MAX_C 4.605170185988091f  // log(100)
#define LOG2E 1.442695040888963f

typedef __bf16 bf16x8 __attribute__((ext_vector_type(8)));
typedef float  f32x4  __attribute__((ext_vector_type(4)));

// native v_exp_f32 (2^x) — NOT __exp2f (glibc macro collision on gfx950 build)
#define EXP2F(x) __builtin_amdgcn_exp2f(x)

// ---------------------------------------------------------------------------
// x (fp32 NCHW, 96ch, 240x240) -> xh (bf16 NHWC, zero-padded 242x242x96).
// ---------------------------------------------------------------------------
__global__ __launch_bounds__(256) void to_nhwc_pad(
    const float* __restrict__ in, __bf16* __restrict__ outh)
{
    const int p = blockIdx.x * 256 + threadIdx.x;
    if (p >= PW * PW) return;
    const int py = p / PW, px = p % PW;
    __bf16* op = outh + p * 96;
    union { __bf16 h[8]; uint4 u; } pk;
    if (py == 0 || py == PW - 1 || px == 0 || px == PW - 1) {
        pk.u = make_uint4(0, 0, 0, 0);
#pragma unroll
        for (int b = 0; b < 12; ++b) ((uint4*)op)[b] = pk.u;
    } else {
        const float* ip = in + (py - 1) * WW + (px - 1);
#pragma unroll
        for (int b = 0; b < 12; ++b) {
#pragma unroll
            for (int j = 0; j < 8; ++j)
                pk.h[j] = (__bf16)ip[(b * 8 + j) * PP];
            ((uint4*)op)[b] = pk.u;
        }
    }
}

// ---------------------------------------------------------------------------
// OIHW fp32 weights -> wt[tap][oc][ic] bf16 (tap = ky*3+kx).
// ---------------------------------------------------------------------------
__global__ __launch_bounds__(256) void wt_transform(
    const float* __restrict__ w, __bf16* __restrict__ wt, int OC)
{
    const int t = blockIdx.x * 256 + threadIdx.x;
    if (t >= OC * 96) return;
    const int oc = t / 96, ic = t % 96;
    const float* wp = w + t * 9;
#pragma unroll
    for (int tap = 0; tap < 9; ++tap)
        wt[(tap * OC + oc) * 96 + ic] = (__bf16)wp[tap];
}

// ---------------------------------------------------------------------------
// Zero only the 1-px border ring of ych (interior is fully overwritten by the
// three attention branches: ch0-31 win0, ch32-63 win1, ch64-95 axial_col).
// ---------------------------------------------------------------------------
__global__ __launch_bounds__(256) void zero_border(__bf16* __restrict__ ych)
{
    const int idx = blockIdx.x * 256 + threadIdx.x;
    if (idx >= 4 * PW) return;
    const int g = idx / PW, i = idx % PW;
    int py, px;
    if (g == 0)      { py = 0;      px = i; }
    else if (g == 1) { py = PW - 1; px = i; }
    else if (g == 2) { py = i;      px = 0; }
    else             { py = i;      px = PW - 1; }
    uint4* op = (uint4*)(ych + (size_t)(py * PW + px) * 96);
#pragma unroll
    for (int b = 0; b < 12; ++b) op[b] = make_uint4(0, 0, 0, 0);
}

// ---------------------------------------------------------------------------
// Implicit-GEMM 3x3 conv on MFMA, v3.
// Round-5 profile: MfmaUtil 12%, VALU 5%, occ 21%, FETCH = 3.4x input ->
// miss-latency bound; the 3 oc-slices each re-stream the image past L2.
// Fixes:
//  (a) XCD-affinity swizzle: 1D grid decoded so the 3 blocks sharing an xy
//      tile (z = 0..2) have block IDs differing by 8 -> same XCD under the
//      %8 round-robin heuristic, within ~24 IDs temporally. Slices 2,3 L2-hit.
//  (b) NT=2 rows/wave -> 5400 waves (2x TLP of round 5).
//  (c) Explicit double-buffered chunk pipeline (load c+1 while MFMA c).
// Wave tile: MT*16 oc x 16 px x 2 rows; block = 4 waves stacked -> 8 rows.
// Chunk c in [0,27): tap = c/3 (dy=tap/3, dx=tap%3), ic-block = c%3.
// C/D layout: col(px) = lane&15, row(oc) = quad*4 + reg  [m89-verified].
// Grid: 1368 blocks = 57 groups x (8 xy-tiles x 3 z); xy >= 450 blocks idle.
// ---------------------------------------------------------------------------
template <int OC, int MT>
__global__ __launch_bounds__(256) void conv3x3_mfma(
    const __bf16* __restrict__ xh, const __bf16* __restrict__ wt,
    const float* __restrict__ bias, float* __restrict__ out)
{
    const int bid   = blockIdx.x;
    const int group = bid / 24;
    const int w24   = bid % 24;
    const int z     = w24 >> 3;
    const int xy    = group * 8 + (w24 & 7);
    if (xy >= 450) return;          // 450 = 15 x-tiles * 30 y-tiles
    const int x0  = (xy % 15) * 16;
    const int y0  = (xy / 15) * 8;
    const int oc0 = z * (MT * 16);

    const int wave = threadIdx.x >> 6;
    const int lane = threadIdx.x & 63;
    const int ln   = lane & 15;
    const int quad = lane >> 4;
    const int r0   = y0 + wave * 2;

    f32x4 acc[MT][2] = {};

    const __bf16* ab = wt + (size_t)(oc0 + ln) * 96 + quad * 8;
    const __bf16* bb = xh + (size_t)(x0 + ln) * 96 + quad * 8;

    bf16x8 a[2][MT], b[2][2];

    // chunk loader: buf <- frags for chunk c
#define LOAD_CHUNK(c, buf)                                                    \
    {                                                                         \
        const int tap_ = (c) / 3, icb_ = (c) % 3;                             \
        const int dy_ = tap_ / 3, dx_ = tap_ % 3;                             \
        const __bf16* ap_ = ab + (size_t)tap_ * OC * 96 + icb_ * 32;          \
        const __bf16* bp_ = bb + ((size_t)(r0 + dy_) * PW + dx_) * 96 + icb_ * 32; \
        _Pragma("unroll")                                                     \
        for (int mi = 0; mi < MT; ++mi)                                       \
            a[buf][mi] = *(const bf16x8*)(ap_ + (size_t)mi * 16 * 96);        \
        _Pragma("unroll")                                                     \
        for (int ni = 0; ni < 2; ++ni)                                        \
            b[buf][ni] = *(const bf16x8*)(bp_ + (size_t)ni * PW * 96);        \
    }

    LOAD_CHUNK(0, 0)
#pragma unroll
    for (int c = 0; c < 27; ++c) {
        const int cur = c & 1, nxt = cur ^ 1;
        if (c < 26) LOAD_CHUNK(c + 1, nxt)
#pragma unroll
        for (int mi = 0; mi < MT; ++mi)
#pragma unroll
            for (int ni = 0; ni < 2; ++ni)
                acc[mi][ni] = __builtin_amdgcn_mfma_f32_16x16x32_bf16(
                    a[cur][mi], b[cur][ni], acc[mi][ni], 0, 0, 0);
    }
#undef LOAD_CHUNK

#pragma unroll
    for (int mi = 0; mi < MT; ++mi) {
#pragma unroll
        for (int r = 0; r < 4; ++r) {
            const int oc = oc0 + mi * 16 + quad * 4 + r;
            const float bv = bias[oc];
#pragma unroll
            for (int ni = 0; ni < 2; ++ni) {
                out[(size_t)oc * PP + (r0 + ni) * WW + x0 + ln] = acc[mi][ni][r] + bv;
            }
        }
    }
}

// ---------------------------------------------------------------------------
// Window cosine attention, WS=5, NH=8, hd=4. Fixed-max single-pass softmax:
// cos*scale <= scale, so p = exp2(dot(q*scale*log2e, k) - scale*log2e) is
// exact softmax math with M = scale. One transcendental per key, no max pass.
// ---------------------------------------------------------------------------
__global__ __launch_bounds__(256) void win_attn_kernel(
    const float* __restrict__ fq, const float* __restrict__ kv,
    const float* __restrict__ lsc, __bf16* __restrict__ ych,
    int gshift, int sshift, int choff)
{
    __shared__ float ks[8][25][4];
    __shared__ float vs[8][25][4];
    const int t = threadIdx.x;
    const int wy = blockIdx.y, wx = blockIdx.x;
    const int h = t / 25, i = t % 25;
    float qn[4] = {0, 0, 0, 0};
    float negM2 = 0.f;
    int oy = 0, ox = 0;

    if (t < 200) {
        const int y = (wy * 5 + i / 5 + gshift) % HH;
        const int x = (wx * 5 + i % 5 + gshift) % WW;
        const int base = y * WW + x;
        float q[4], k[4];
        float qsq = 0.f, ksq = 0.f;
#pragma unroll
        for (int d = 0; d < 4; ++d) {
            q[d] = fq[(h * 4 + d) * PP + base];
            k[d] = kv[(h * 4 + d) * PP + base];
            vs[h][i][d] = kv[((8 + h) * 4 + d) * PP + base];
            qsq += q[d] * q[d];
            ksq += k[d] * k[d];
        }
        const float scale = __expf(fminf(lsc[h], LOG_MAX_C));
        const float qs = scale * LOG2E;
        negM2 = -qs;
        const float qinv = qs / fmaxf(sqrtf(qsq), 1e-12f);
        const float kinv = 1.0f / fmaxf(sqrtf(ksq), 1e-12f);
#pragma unroll
        for (int d = 0; d < 4; ++d) {
            qn[d] = q[d] * qinv;
            ks[h][i][d] = k[d] * kinv;
        }
        oy = (wy * 5 + i / 5 + sshift) % HH;
        ox = (wx * 5 + i % 5 + sshift) % WW;
    }
    __syncthreads();
    if (t < 200) {
        float l = 0.f, acc[4] = {0, 0, 0, 0};
#pragma unroll
        for (int j = 0; j < 25; ++j) {
            const float s = fmaf(qn[0], ks[h][j][0],
                            fmaf(qn[1], ks[h][j][1],
                            fmaf(qn[2], ks[h][j][2],
                            fmaf(qn[3], ks[h][j][3], negM2))));
            const float p = EXP2F(s);
            l += p;
#pragma unroll
            for (int d = 0; d < 4; ++d) acc[d] = fmaf(p, vs[h][j][d], acc[d]);
        }
        const float linv = 1.0f / l;
        union { __bf16 h4[4]; uint2 u; } o;
#pragma unroll
        for (int d = 0; d < 4; ++d) o.h4[d] = (__bf16)(acc[d] * linv);
        *(uint2*)(ych + (size_t)((oy + 1) * PW + ox + 1) * 96 + choff + h * 4) = o.u;
    }
}

// ---------------------------------------------------------------------------
// Axial row attention (over w). One block per (row y, head h); t = query x.
// ---------------------------------------------------------------------------
__global__ __launch_bounds__(256) void axial_row_kernel(
    const float* __restrict__ fq, const float* __restrict__ kv,
    const float* __restrict__ lsc, float* __restrict__ v1)
{
    __shared__ float ks[240][4];
    __shared__ float vs[240][4];
    const int t = threadIdx.x;
    const int y = blockIdx.x, h = blockIdx.y;

    float q[4] = {0, 0, 0, 0};
    float negM2 = 0.f;
    if (t < 240) {
        float k[4];
        float ksq = 0.f, qsq = 0.f;
#pragma unroll
        for (int d = 0; d < 4; ++d) {
            k[d] = kv[(h * 4 + d) * PP + y * WW + t];
            vs[t][d] = kv[((8 + h) * 4 + d) * PP + y * WW + t];
            q[d] = fq[(h * 4 + d) * PP + y * WW + t];
            ksq += k[d] * k[d];
            qsq += q[d] * q[d];
        }
        const float kinv = 1.0f / fmaxf(sqrtf(ksq), 1e-12f);
#pragma unroll
        for (int d = 0; d < 4; ++d) ks[t][d] = k[d] * kinv;
        const float scale = __expf(fminf(lsc[h], LOG_MAX_C));
        const float qs = scale * LOG2E;
        negM2 = -qs;
        const float qinv = qs / fmaxf(sqrtf(qsq), 1e-12f);
#pragma unroll
        for (int d = 0; d < 4; ++d) q[d] *= qinv;
    }
    __syncthreads();
    if (t < 240) {
        float l = 0.f, acc[4] = {0, 0, 0, 0};
        for (int j = 0; j < 240; ++j) {
            const float s = fmaf(q[0], ks[j][0],
                            fmaf(q[1], ks[j][1],
                            fmaf(q[2], ks[j][2],
                            fmaf(q[3], ks[j][3], negM2))));
            const float p = EXP2F(s);
            l += p;
#pragma unroll
            for (int d = 0; d < 4; ++d) acc[d] = fmaf(p, vs[j][d], acc[d]);
        }
        const float linv = 1.0f / l;
#pragma unroll
        for (int d = 0; d < 4; ++d)
            v1[(h * 4 + d) * PP + y * WW + t] = acc[d] * linv;
    }
}

// ---------------------------------------------------------------------------
// Axial column attention (over h), same normalized q/k, V = v1 (row output).
// ---------------------------------------------------------------------------
__global__ __launch_bounds__(256) void axial_col_kernel(
    const float* __restrict__ fq, const float* __restrict__ kv,
    const float* __restrict__ v1, const float* __restrict__ lsc,
    __bf16* __restrict__ ych)
{
    __shared__ float ks[240][4];
    __shared__ float vs[240][4];
    const int t = threadIdx.x;
    const int x = blockIdx.x, h = blockIdx.y;

    float q[4] = {0, 0, 0, 0};
    float negM2 = 0.f;
    if (t < 240) {
        float k[4];
        float ksq = 0.f, qsq = 0.f;
#pragma unroll
        for (int d = 0; d < 4; ++d) {
            k[d] = kv[(h * 4 + d) * PP + t * WW + x];
            vs[t][d] = v1[(h * 4 + d) * PP + t * WW + x];
            q[d] = fq[(h * 4 + d) * PP + t * WW + x];
            ksq += k[d] * k[d];
            qsq += q[d] * q[d];
        }
        const float kinv = 1.0f / fmaxf(sqrtf(ksq), 1e-12f);
#pragma unroll
        for (int d = 0; d < 4; ++d) ks[t][d] = k[d] * kinv;
        const float scale = __expf(fminf(lsc[h], LOG_MAX_C));
        const float qs = scale * LOG2E;
        negM2 = -qs;
        const float qinv = qs / fmaxf(sqrtf(qsq), 1e-12f);
#pragma unroll
        for (int d = 0; d < 4; ++d) q[d] *= qinv;
    }
    __syncthreads();
    if (t < 240) {
        float l = 0.f, acc[4] = {0, 0, 0, 0};
        for (int j = 0; j < 240; ++j) {
            const float s = fmaf(q[0], ks[j][0],
                            fmaf(q[1], ks[j][1],
                            fmaf(q[2], ks[j][2],
                            fmaf(q[3], ks[j][3], negM2))));
            const float p = EXP2F(s);
            l += p;
#pragma unroll
            for (int d = 0; d < 4; ++d) acc[d] = fmaf(p, vs[j][d], acc[d]);
        }
        const float linv = 1.0f / l;
        union { __bf16 h4[4]; uint2 u; } o;
#pragma unroll
        for (int d = 0; d < 4; ++d) o.h4[d] = (__bf16)(acc[d] * linv);
        *(uint2*)(ych + (size_t)((t + 1) * PW + x + 1) * 96 + 64 + h * 4) = o.u;
    }
}

// ---------------------------------------------------------------------------
// Pipeline (see round-2 comments).
// ---------------------------------------------------------------------------
extern "C" void kernel_launch(void* const* d_in, const int* in_sizes, int n_in,
                              void* d_out, int out_size, void* d_ws, size_t ws_size,
                              hipStream_t stream)
{
    const float* x     = (const float*)d_in[0];
    const float* w_in  = (const float*)d_in[1];
    const float* b_in  = (const float*)d_in[2];
    const float* w_f   = (const float*)d_in[3];
    const float* b_f   = (const float*)d_in[4];
    const float* w_out = (const float*)d_in[5];
    const float* b_out = (const float*)d_in[6];
    const float* lsc   = (const float*)d_in[7];
    const float* lrlsc = (const float*)d_in[8];
    float* out = (float*)d_out;

    float* ws = (float*)d_ws;
    float* xp = ws;                    // 192*PP f32
    float* fp = xp + 192 * PP;         //  96*PP f32
    float* v1 = fp + 96 * PP;          //  32*PP f32
    __bf16* xh    = (__bf16*)(v1 + 32 * PP);          // 242*242*96 bf16 (= ych)
    __bf16* wt_in = xh + (size_t)PW * PW * 96;        // 9*192*96
    __bf16* wt_f  = wt_in + 9 * 192 * 96;             // 9*96*96
    __bf16* wt_o  = wt_f + 9 * 96 * 96;               // 9*96*96
    __bf16* ych   = xh;                                // alias: xh dead after convs

    wt_transform<<<(192 * 96 + 255) / 256, 256, 0, stream>>>(w_in, wt_in, 192);
    wt_transform<<<(96 * 96 + 255) / 256, 256, 0, stream>>>(w_f, wt_f, 96);
    wt_transform<<<(96 * 96 + 255) / 256, 256, 0, stream>>>(w_out, wt_o, 96);
    to_nhwc_pad<<<(PW * PW + 255) / 256, 256, 0, stream>>>(x, xh);

    // convs (MFMA implicit GEMM, v3): 1368-block 1D grid with XCD swizzle
    conv3x3_mfma<192, 4><<<1368, 256, 0, stream>>>(xh, wt_in, b_in, xp);
    conv3x3_mfma<96, 2><<<1368, 256, 0, stream>>>(xh, wt_f, b_f, fp);

    // border-only clear of ych (interior fully overwritten by attention)
    zero_border<<<(4 * PW + 255) / 256, 256, 0, stream>>>(ych);

    win_attn_kernel<<<dim3(48, 48), 256, 0, stream>>>(fp, xp, lsc, ych, 0, 0, 0);
    win_attn_kernel<<<dim3(48, 48), 256, 0, stream>>>(fp + 32 * PP, xp + 64 * PP,
                                                      lsc, ych, 3, 2, 32);
    axial_row_kernel<<<dim3(240, 8), 256, 0, stream>>>(fp + 64 * PP, xp + 128 * PP,
                                                       lrlsc, v1);
    axial_col_kernel<<<dim3(240, 8), 256, 0, stream>>>(fp + 64 * PP, xp + 128 * PP,
                                                       v1, lrlsc, ych);

    conv3x3_mfma<96, 2><<<1368, 256, 0, stream>>>(ych, wt_o, b_out, out);
}

// Round 7
// 340.272 us; speedup vs baseline: 1.1205x; 1.1205x over previous
//
#include <hip/hip_runtime.h>
#include <math.h>

#define HH 240
#define WW 240
#define PP (HH * WW)
#define PW 242              // padded height/width for conv input
#define LOG_MAX_C 4.605170185988091f  // log(100)
#define LOG2E 1.442695040888963f

typedef __bf16 bf16x8 __attribute__((ext_vector_type(8)));
typedef float  f32x4  __attribute__((ext_vector_type(4)));

// native v_exp_f32 (2^x) — NOT __exp2f (glibc macro collision on gfx950 build)
#define EXP2F(x) __builtin_amdgcn_exp2f(x)

// ===========================================================================
// Fragment-native input layout (kills VMEM address divergence, r6 post-mortem:
// NHWC frag loads touched 16 discontiguous lines/instr -> TA-throughput wall):
//   xs[row(242)][icb(3)][px(242)][32 ch-elems]   (bf16)
// B-fragment load for (row, icb, px0): lane(quad*16+ln) reads elem
//   ((row*3+icb)*242 + px0)*32 + ln*32 + quad*8  -> wave covers one
//   contiguous 1 KB span = single ideal transaction.
// Weights: wtf[tap][ocb][icb][lane*8 elems] -> A-frag = lane*16B, ideal.
// ===========================================================================

// ---------------------------------------------------------------------------
// x (fp32 NCHW) -> xs (bf16 fragment layout, zero-padded ring).
// ---------------------------------------------------------------------------
__global__ __launch_bounds__(256) void to_xs_pad(
    const float* __restrict__ in, __bf16* __restrict__ xs)
{
    const int p = blockIdx.x * 256 + threadIdx.x;
    if (p >= PW * PW) return;
    const int row = p / PW, px = p % PW;
    const bool border = (row == 0 || row == PW - 1 || px == 0 || px == PW - 1);
    union { __bf16 h[32]; uint4 u[4]; } pk;
#pragma unroll
    for (int icb = 0; icb < 3; ++icb) {
        uint4* op = (uint4*)(xs + (((size_t)row * 3 + icb) * PW + px) * 32);
        if (border) {
#pragma unroll
            for (int b = 0; b < 4; ++b) op[b] = make_uint4(0, 0, 0, 0);
        } else {
            const float* ip = in + (size_t)(icb * 32) * PP + (row - 1) * WW + (px - 1);
#pragma unroll
            for (int j = 0; j < 32; ++j) pk.h[j] = (__bf16)ip[(size_t)j * PP];
#pragma unroll
            for (int b = 0; b < 4; ++b) op[b] = pk.u[b];
        }
    }
}

// ---------------------------------------------------------------------------
// OIHW fp32 -> wtf fragment layout: wtf[((tap*(OC/16)+ocb)*3+icb)*512 + lane*8]
// lane = quad*16+ln; oc = ocb*16+ln; ic = icb*32+quad*8 .. +8.
// One thread per (tap, ocb, icb, lane).
// ---------------------------------------------------------------------------
__global__ __launch_bounds__(256) void wt_frag(
    const float* __restrict__ w, __bf16* __restrict__ wtf, int OC)
{
    const int t = blockIdx.x * 256 + threadIdx.x;
    if (t >= 9 * (OC / 16) * 3 * 64) return;
    const int lane = t & 63;
    const int rest = t >> 6;                 // (tap*(OC/16)+ocb)*3+icb
    const int icb  = rest % 3;
    const int to   = rest / 3;
    const int ocb  = to % (OC / 16);
    const int tap  = to / (OC / 16);
    const int ln = lane & 15, quad = lane >> 4;
    const int oc  = ocb * 16 + ln;
    const int ic0 = icb * 32 + quad * 8;
    __bf16* op = wtf + (size_t)rest * 512 + lane * 8;
#pragma unroll
    for (int d = 0; d < 8; ++d)
        op[d] = (__bf16)w[(size_t)(oc * 96 + ic0 + d) * 9 + tap];
}

// ---------------------------------------------------------------------------
// Zero the 1-px border ring of ys (fragment layout). Interior fully
// overwritten by the three attention branches.
// ---------------------------------------------------------------------------
__global__ __launch_bounds__(256) void zero_border_xs(__bf16* __restrict__ ys)
{
    const int idx = blockIdx.x * 256 + threadIdx.x;
    if (idx >= 4 * PW) return;
    const int g = idx / PW, i = idx % PW;
    int row, px;
    if (g == 0)      { row = 0;      px = i; }
    else if (g == 1) { row = PW - 1; px = i; }
    else if (g == 2) { row = i;      px = 0; }
    else             { row = i;      px = PW - 1; }
#pragma unroll
    for (int icb = 0; icb < 3; ++icb) {
        uint4* op = (uint4*)(ys + (((size_t)row * 3 + icb) * PW + px) * 32);
#pragma unroll
        for (int b = 0; b < 4; ++b) op[b] = make_uint4(0, 0, 0, 0);
    }
}

// ---------------------------------------------------------------------------
// Implicit-GEMM 3x3 conv on MFMA, v4: fragment-native layouts -> every A/B
// load is one contiguous 1 KB wave transaction. Keeps r6's XCD-affinity
// swizzle (proven: FETCH 38->9.8 MB) and double-buffered chunk pipeline.
// Wave tile: MT*16 oc x 16 px x 2 rows; block = 4 waves -> 8 rows.
// Chunk c in [0,27): tap = c/3 (dy,dx), icb = c%3.
// C/D layout: col(px) = lane&15, row(oc) = quad*4 + reg  [m89-verified].
// ---------------------------------------------------------------------------
template <int OC, int MT>
__global__ __launch_bounds__(256) void conv3x3_mfma(
    const __bf16* __restrict__ xs, const __bf16* __restrict__ wtf,
    const float* __restrict__ bias, float* __restrict__ out)
{
    const int bid   = blockIdx.x;
    const int group = bid / 24;
    const int w24   = bid % 24;
    const int z     = w24 >> 3;
    const int xy    = group * 8 + (w24 & 7);
    if (xy >= 450) return;          // 15 x-tiles * 30 y-tiles
    const int x0  = (xy % 15) * 16;
    const int y0  = (xy / 15) * 8;
    const int oc0 = z * (MT * 16);
    const int ocb0 = oc0 / 16;

    const int wave = threadIdx.x >> 6;
    const int lane = threadIdx.x & 63;
    const int ln   = lane & 15;
    const int quad = lane >> 4;
    const int r0   = y0 + wave * 2;

    f32x4 acc[MT][2] = {};
    bf16x8 a[2][MT], b[2][2];

    const __bf16* abase = wtf + (size_t)lane * 8;
    const __bf16* bbase = xs + (size_t)ln * 32 + quad * 8;

#define LOAD_CHUNK(c, buf)                                                    \
    {                                                                         \
        const int tap_ = (c) / 3, icb_ = (c) % 3;                             \
        const int dy_ = tap_ / 3, dx_ = tap_ % 3;                             \
        const __bf16* ap_ = abase + (size_t)((tap_ * (OC / 16) + ocb0) * 3 + icb_) * 512; \
        _Pragma("unroll")                                                     \
        for (int mi = 0; mi < MT; ++mi)                                       \
            a[buf][mi] = *(const bf16x8*)(ap_ + (size_t)mi * 1536);           \
        _Pragma("unroll")                                                     \
        for (int ni = 0; ni < 2; ++ni)                                        \
            b[buf][ni] = *(const bf16x8*)(bbase +                             \
                (((size_t)(r0 + ni + dy_) * 3 + icb_) * PW + x0 + dx_) * 32); \
    }

    LOAD_CHUNK(0, 0)
#pragma unroll
    for (int c = 0; c < 27; ++c) {
        const int cur = c & 1, nxt = cur ^ 1;
        if (c < 26) LOAD_CHUNK(c + 1, nxt)
#pragma unroll
        for (int mi = 0; mi < MT; ++mi)
#pragma unroll
            for (int ni = 0; ni < 2; ++ni)
                acc[mi][ni] = __builtin_amdgcn_mfma_f32_16x16x32_bf16(
                    a[cur][mi], b[cur][ni], acc[mi][ni], 0, 0, 0);
    }
#undef LOAD_CHUNK

#pragma unroll
    for (int mi = 0; mi < MT; ++mi) {
#pragma unroll
        for (int r = 0; r < 4; ++r) {
            const int oc = oc0 + mi * 16 + quad * 4 + r;
            const float bv = bias[oc];
#pragma unroll
            for (int ni = 0; ni < 2; ++ni) {
                out[(size_t)oc * PP + (r0 + ni) * WW + x0 + ln] = acc[mi][ni][r] + bv;
            }
        }
    }
}

// ---------------------------------------------------------------------------
// Window cosine attention, WS=5, NH=8, hd=4. Fixed-max single-pass softmax.
// Writes bf16 4-ch chunk into ys fragment layout at (row+1, px+1, icb, h*4).
// ---------------------------------------------------------------------------
__global__ __launch_bounds__(256) void win_attn_kernel(
    const float* __restrict__ fq, const float* __restrict__ kv,
    const float* __restrict__ lsc, __bf16* __restrict__ ys,
    int gshift, int sshift, int icb)
{
    __shared__ float ks[8][25][4];
    __shared__ float vs[8][25][4];
    const int t = threadIdx.x;
    const int wy = blockIdx.y, wx = blockIdx.x;
    const int h = t / 25, i = t % 25;
    float qn[4] = {0, 0, 0, 0};
    float negM2 = 0.f;
    int oy = 0, ox = 0;

    if (t < 200) {
        const int y = (wy * 5 + i / 5 + gshift) % HH;
        const int x = (wx * 5 + i % 5 + gshift) % WW;
        const int base = y * WW + x;
        float q[4], k[4];
        float qsq = 0.f, ksq = 0.f;
#pragma unroll
        for (int d = 0; d < 4; ++d) {
            q[d] = fq[(h * 4 + d) * PP + base];
            k[d] = kv[(h * 4 + d) * PP + base];
            vs[h][i][d] = kv[((8 + h) * 4 + d) * PP + base];
            qsq += q[d] * q[d];
            ksq += k[d] * k[d];
        }
        const float scale = __expf(fminf(lsc[h], LOG_MAX_C));
        const float qs = scale * LOG2E;
        negM2 = -qs;
        const float qinv = qs / fmaxf(sqrtf(qsq), 1e-12f);
        const float kinv = 1.0f / fmaxf(sqrtf(ksq), 1e-12f);
#pragma unroll
        for (int d = 0; d < 4; ++d) {
            qn[d] = q[d] * qinv;
            ks[h][i][d] = k[d] * kinv;
        }
        oy = (wy * 5 + i / 5 + sshift) % HH;
        ox = (wx * 5 + i % 5 + sshift) % WW;
    }
    __syncthreads();
    if (t < 200) {
        float l = 0.f, acc[4] = {0, 0, 0, 0};
#pragma unroll
        for (int j = 0; j < 25; ++j) {
            const float s = fmaf(qn[0], ks[h][j][0],
                            fmaf(qn[1], ks[h][j][1],
                            fmaf(qn[2], ks[h][j][2],
                            fmaf(qn[3], ks[h][j][3], negM2))));
            const float p = EXP2F(s);
            l += p;
#pragma unroll
            for (int d = 0; d < 4; ++d) acc[d] = fmaf(p, vs[h][j][d], acc[d]);
        }
        const float linv = 1.0f / l;
        union { __bf16 h4[4]; uint2 u; } o;
#pragma unroll
        for (int d = 0; d < 4; ++d) o.h4[d] = (__bf16)(acc[d] * linv);
        *(uint2*)(ys + (((size_t)(oy + 1) * 3 + icb) * PW + ox + 1) * 32 + h * 4) = o.u;
    }
}

// ---------------------------------------------------------------------------
// Axial row attention (over w). One block per (row y, head h); t = query x.
// ---------------------------------------------------------------------------
__global__ __launch_bounds__(256) void axial_row_kernel(
    const float* __restrict__ fq, const float* __restrict__ kv,
    const float* __restrict__ lsc, float* __restrict__ v1)
{
    __shared__ float ks[240][4];
    __shared__ float vs[240][4];
    const int t = threadIdx.x;
    const int y = blockIdx.x, h = blockIdx.y;

    float q[4] = {0, 0, 0, 0};
    float negM2 = 0.f;
    if (t < 240) {
        float k[4];
        float ksq = 0.f, qsq = 0.f;
#pragma unroll
        for (int d = 0; d < 4; ++d) {
            k[d] = kv[(h * 4 + d) * PP + y * WW + t];
            vs[t][d] = kv[((8 + h) * 4 + d) * PP + y * WW + t];
            q[d] = fq[(h * 4 + d) * PP + y * WW + t];
            ksq += k[d] * k[d];
            qsq += q[d] * q[d];
        }
        const float kinv = 1.0f / fmaxf(sqrtf(ksq), 1e-12f);
#pragma unroll
        for (int d = 0; d < 4; ++d) ks[t][d] = k[d] * kinv;
        const float scale = __expf(fminf(lsc[h], LOG_MAX_C));
        const float qs = scale * LOG2E;
        negM2 = -qs;
        const float qinv = qs / fmaxf(sqrtf(qsq), 1e-12f);
#pragma unroll
        for (int d = 0; d < 4; ++d) q[d] *= qinv;
    }
    __syncthreads();
    if (t < 240) {
        float l = 0.f, acc[4] = {0, 0, 0, 0};
        for (int j = 0; j < 240; ++j) {
            const float s = fmaf(q[0], ks[j][0],
                            fmaf(q[1], ks[j][1],
                            fmaf(q[2], ks[j][2],
                            fmaf(q[3], ks[j][3], negM2))));
            const float p = EXP2F(s);
            l += p;
#pragma unroll
            for (int d = 0; d < 4; ++d) acc[d] = fmaf(p, vs[j][d], acc[d]);
        }
        const float linv = 1.0f / l;
#pragma unroll
        for (int d = 0; d < 4; ++d)
            v1[(h * 4 + d) * PP + y * WW + t] = acc[d] * linv;
    }
}

// ---------------------------------------------------------------------------
// Axial column attention (over h), same normalized q/k, V = v1 (row output).
// Writes ys fragment layout at icb=2.
// ---------------------------------------------------------------------------
__global__ __launch_bounds__(256) void axial_col_kernel(
    const float* __restrict__ fq, const float* __restrict__ kv,
    const float* __restrict__ v1, const float* __restrict__ lsc,
    __bf16* __restrict__ ys)
{
    __shared__ float ks[240][4];
    __shared__ float vs[240][4];
    const int t = threadIdx.x;
    const int x = blockIdx.x, h = blockIdx.y;

    float q[4] = {0, 0, 0, 0};
    float negM2 = 0.f;
    if (t < 240) {
        float k[4];
        float ksq = 0.f, qsq = 0.f;
#pragma unroll
        for (int d = 0; d < 4; ++d) {
            k[d] = kv[(h * 4 + d) * PP + t * WW + x];
            vs[t][d] = v1[(h * 4 + d) * PP + t * WW + x];
            q[d] = fq[(h * 4 + d) * PP + t * WW + x];
            ksq += k[d] * k[d];
            qsq += q[d] * q[d];
        }
        const float kinv = 1.0f / fmaxf(sqrtf(ksq), 1e-12f);
#pragma unroll
        for (int d = 0; d < 4; ++d) ks[t][d] = k[d] * kinv;
        const float scale = __expf(fminf(lsc[h], LOG_MAX_C));
        const float qs = scale * LOG2E;
        negM2 = -qs;
        const float qinv = qs / fmaxf(sqrtf(qsq), 1e-12f);
#pragma unroll
        for (int d = 0; d < 4; ++d) q[d] *= qinv;
    }
    __syncthreads();
    if (t < 240) {
        float l = 0.f, acc[4] = {0, 0, 0, 0};
        for (int j = 0; j < 240; ++j) {
            const float s = fmaf(q[0], ks[j][0],
                            fmaf(q[1], ks[j][1],
                            fmaf(q[2], ks[j][2],
                            fmaf(q[3], ks[j][3], negM2))));
            const float p = EXP2F(s);
            l += p;
#pragma unroll
            for (int d = 0; d < 4; ++d) acc[d] = fmaf(p, vs[j][d], acc[d]);
        }
        const float linv = 1.0f / l;
        union { __bf16 h4[4]; uint2 u; } o;
#pragma unroll
        for (int d = 0; d < 4; ++d) o.h4[d] = (__bf16)(acc[d] * linv);
        *(uint2*)(ys + (((size_t)(t + 1) * 3 + 2) * PW + x + 1) * 32 + h * 4) = o.u;
    }
}

// ---------------------------------------------------------------------------
// Pipeline: wt_frag x3; x -> xs; conv_in/conv_f (MFMA v4, fragment layouts);
// zero ys border (ys aliases xs); attention -> ys; conv_out -> d_out.
// ---------------------------------------------------------------------------
extern "C" void kernel_launch(void* const* d_in, const int* in_sizes, int n_in,
                              void* d_out, int out_size, void* d_ws, size_t ws_size,
                              hipStream_t stream)
{
    const float* x     = (const float*)d_in[0];
    const float* w_in  = (const float*)d_in[1];
    const float* b_in  = (const float*)d_in[2];
    const float* w_f   = (const float*)d_in[3];
    const float* b_f   = (const float*)d_in[4];
    const float* w_out = (const float*)d_in[5];
    const float* b_out = (const float*)d_in[6];
    const float* lsc   = (const float*)d_in[7];
    const float* lrlsc = (const float*)d_in[8];
    float* out = (float*)d_out;

    float* ws = (float*)d_ws;
    float* xp = ws;                    // 192*PP f32
    float* fp = xp + 192 * PP;         //  96*PP f32
    float* v1 = fp + 96 * PP;          //  32*PP f32
    __bf16* xs     = (__bf16*)(v1 + 32 * PP);             // 242*3*242*32 bf16
    __bf16* wtf_in = xs + (size_t)PW * 3 * PW * 32;       // 9*12*3*512
    __bf16* wtf_f  = wtf_in + 9 * 12 * 3 * 512;           // 9*6*3*512
    __bf16* wtf_o  = wtf_f + 9 * 6 * 3 * 512;             // 9*6*3*512
    __bf16* ys     = xs;               // alias: xs dead after conv_in/conv_f

    wt_frag<<<(9 * 12 * 3 * 64 + 255) / 256, 256, 0, stream>>>(w_in, wtf_in, 192);
    wt_frag<<<(9 * 6 * 3 * 64 + 255) / 256, 256, 0, stream>>>(w_f, wtf_f, 96);
    wt_frag<<<(9 * 6 * 3 * 64 + 255) / 256, 256, 0, stream>>>(w_out, wtf_o, 96);
    to_xs_pad<<<(PW * PW + 255) / 256, 256, 0, stream>>>(x, xs);

    // convs (MFMA v4): 1368-block 1D grid with XCD swizzle
    conv3x3_mfma<192, 4><<<1368, 256, 0, stream>>>(xs, wtf_in, b_in, xp);
    conv3x3_mfma<96, 2><<<1368, 256, 0, stream>>>(xs, wtf_f, b_f, fp);

    zero_border_xs<<<(4 * PW + 255) / 256, 256, 0, stream>>>(ys);

    win_attn_kernel<<<dim3(48, 48), 256, 0, stream>>>(fp, xp, lsc, ys, 0, 0, 0);
    win_attn_kernel<<<dim3(48, 48), 256, 0, stream>>>(fp + 32 * PP, xp + 64 * PP,
                                                      lsc, ys, 3, 2, 1);
    axial_row_kernel<<<dim3(240, 8), 256, 0, stream>>>(fp + 64 * PP, xp + 128 * PP,
                                                       lrlsc, v1);
    axial_col_kernel<<<dim3(240, 8), 256, 0, stream>>>(fp + 64 * PP, xp + 128 * PP,
                                                       v1, lrlsc, ys);

    conv3x3_mfma<96, 2><<<1368, 256, 0, stream>>>(ys, wtf_o, b_out, out);
}

// Round 8
// 305.824 us; speedup vs baseline: 1.2467x; 1.1126x over previous
//
#include <hip/hip_runtime.h>
#include <math.h>

#define HH 240
#define WW 240
#define PP (HH * WW)
#define PW 242              // padded height/width for conv input
#define LOG_MAX_C 4.605170185988091f  // log(100)
#define LOG2E 1.442695040888963f

typedef __bf16 bf16x8 __attribute__((ext_vector_type(8)));
typedef float  f32x4  __attribute__((ext_vector_type(4)));

// native v_exp_f32 (2^x) — NOT __exp2f (glibc macro collision on gfx950 build)
#define EXP2F(x) __builtin_amdgcn_exp2f(x)

// ===========================================================================
// Fragment-native input layout (r7, verified: conv FETCH ~10 MB, convs off
// the top-5): xs[row(242)][icb(3)][px(242)][32 ch]  (bf16).
// B-frag load = one contiguous 1 KB wave transaction.
// Weights: wtf[tap][ocb][icb][lane*8] -> A-frag = lane*16B, ideal.
// ===========================================================================

__global__ __launch_bounds__(256) void to_xs_pad(
    const float* __restrict__ in, __bf16* __restrict__ xs)
{
    const int p = blockIdx.x * 256 + threadIdx.x;
    if (p >= PW * PW) return;
    const int row = p / PW, px = p % PW;
    const bool border = (row == 0 || row == PW - 1 || px == 0 || px == PW - 1);
    union { __bf16 h[32]; uint4 u[4]; } pk;
#pragma unroll
    for (int icb = 0; icb < 3; ++icb) {
        uint4* op = (uint4*)(xs + (((size_t)row * 3 + icb) * PW + px) * 32);
        if (border) {
#pragma unroll
            for (int b = 0; b < 4; ++b) op[b] = make_uint4(0, 0, 0, 0);
        } else {
            const float* ip = in + (size_t)(icb * 32) * PP + (row - 1) * WW + (px - 1);
#pragma unroll
            for (int j = 0; j < 32; ++j) pk.h[j] = (__bf16)ip[(size_t)j * PP];
#pragma unroll
            for (int b = 0; b < 4; ++b) op[b] = pk.u[b];
        }
    }
}

__global__ __launch_bounds__(256) void wt_frag(
    const float* __restrict__ w, __bf16* __restrict__ wtf, int OC)
{
    const int t = blockIdx.x * 256 + threadIdx.x;
    if (t >= 9 * (OC / 16) * 3 * 64) return;
    const int lane = t & 63;
    const int rest = t >> 6;
    const int icb  = rest % 3;
    const int to   = rest / 3;
    const int ocb  = to % (OC / 16);
    const int tap  = to / (OC / 16);
    const int ln = lane & 15, quad = lane >> 4;
    const int oc  = ocb * 16 + ln;
    const int ic0 = icb * 32 + quad * 8;
    __bf16* op = wtf + (size_t)rest * 512 + lane * 8;
#pragma unroll
    for (int d = 0; d < 8; ++d)
        op[d] = (__bf16)w[(size_t)(oc * 96 + ic0 + d) * 9 + tap];
}

__global__ __launch_bounds__(256) void zero_border_xs(__bf16* __restrict__ ys)
{
    const int idx = blockIdx.x * 256 + threadIdx.x;
    if (idx >= 4 * PW) return;
    const int g = idx / PW, i = idx % PW;
    int row, px;
    if (g == 0)      { row = 0;      px = i; }
    else if (g == 1) { row = PW - 1; px = i; }
    else if (g == 2) { row = i;      px = 0; }
    else             { row = i;      px = PW - 1; }
#pragma unroll
    for (int icb = 0; icb < 3; ++icb) {
        uint4* op = (uint4*)(ys + (((size_t)row * 3 + icb) * PW + px) * 32);
#pragma unroll
        for (int b = 0; b < 4; ++b) op[b] = make_uint4(0, 0, 0, 0);
    }
}

// ---------------------------------------------------------------------------
// Implicit-GEMM 3x3 conv on MFMA, v4 (r7, verified). XCD-affinity swizzle +
// fragment-native global loads + double-buffered chunk pipeline.
// ---------------------------------------------------------------------------
template <int OC, int MT>
__global__ __launch_bounds__(256) void conv3x3_mfma(
    const __bf16* __restrict__ xs, const __bf16* __restrict__ wtf,
    const float* __restrict__ bias, float* __restrict__ out)
{
    const int bid   = blockIdx.x;
    const int group = bid / 24;
    const int w24   = bid % 24;
    const int z     = w24 >> 3;
    const int xy    = group * 8 + (w24 & 7);
    if (xy >= 450) return;
    const int x0  = (xy % 15) * 16;
    const int y0  = (xy / 15) * 8;
    const int oc0 = z * (MT * 16);
    const int ocb0 = oc0 / 16;

    const int wave = threadIdx.x >> 6;
    const int lane = threadIdx.x & 63;
    const int ln   = lane & 15;
    const int quad = lane >> 4;
    const int r0   = y0 + wave * 2;

    f32x4 acc[MT][2] = {};
    bf16x8 a[2][MT], b[2][2];

    const __bf16* abase = wtf + (size_t)lane * 8;
    const __bf16* bbase = xs + (size_t)ln * 32 + quad * 8;

#define LOAD_CHUNK(c, buf)                                                    \
    {                                                                         \
        const int tap_ = (c) / 3, icb_ = (c) % 3;                             \
        const int dy_ = tap_ / 3, dx_ = tap_ % 3;                             \
        const __bf16* ap_ = abase + (size_t)((tap_ * (OC / 16) + ocb0) * 3 + icb_) * 512; \
        _Pragma("unroll")                                                     \
        for (int mi = 0; mi < MT; ++mi)                                       \
            a[buf][mi] = *(const bf16x8*)(ap_ + (size_t)mi * 1536);           \
        _Pragma("unroll")                                                     \
        for (int ni = 0; ni < 2; ++ni)                                        \
            b[buf][ni] = *(const bf16x8*)(bbase +                             \
                (((size_t)(r0 + ni + dy_) * 3 + icb_) * PW + x0 + dx_) * 32); \
    }

    LOAD_CHUNK(0, 0)
#pragma unroll
    for (int c = 0; c < 27; ++c) {
        const int cur = c & 1, nxt = cur ^ 1;
        if (c < 26) LOAD_CHUNK(c + 1, nxt)
#pragma unroll
        for (int mi = 0; mi < MT; ++mi)
#pragma unroll
            for (int ni = 0; ni < 2; ++ni)
                acc[mi][ni] = __builtin_amdgcn_mfma_f32_16x16x32_bf16(
                    a[cur][mi], b[cur][ni], acc[mi][ni], 0, 0, 0);
    }
#undef LOAD_CHUNK

#pragma unroll
    for (int mi = 0; mi < MT; ++mi) {
#pragma unroll
        for (int r = 0; r < 4; ++r) {
            const int oc = oc0 + mi * 16 + quad * 4 + r;
            const float bv = bias[oc];
#pragma unroll
            for (int ni = 0; ni < 2; ++ni) {
                out[(size_t)oc * PP + (r0 + ni) * WW + x0 + ln] = acc[mi][ni][r] + bv;
            }
        }
    }
}

// ---------------------------------------------------------------------------
// Window cosine attention, WS=5, NH=8, hd=4. Fixed-max single-pass softmax.
// v2: 1D grid (2304) with XCD swizzle — 8 consecutive-x windows (sharing
// 64B lines along image rows) land on one XCD: i=bid/288, g=bid%288,
// wy=g/6, wx=(g%6)*8+i; 288%8==0 so bid%8 == g%8.
// ---------------------------------------------------------------------------
__global__ __launch_bounds__(256) void win_attn_kernel(
    const float* __restrict__ fq, const float* __restrict__ kv,
    const float* __restrict__ lsc, __bf16* __restrict__ ys,
    int gshift, int sshift, int icb)
{
    __shared__ float ks[8][25][4];
    __shared__ float vs[8][25][4];
    const int bid = blockIdx.x;
    const int wi  = bid / 288;
    const int g   = bid % 288;
    const int wy  = g / 6;
    const int wx  = (g % 6) * 8 + wi;
    const int t = threadIdx.x;
    const int h = t / 25, i = t % 25;
    float qn[4] = {0, 0, 0, 0};
    float negM2 = 0.f;
    int oy = 0, ox = 0;

    if (t < 200) {
        const int y = (wy * 5 + i / 5 + gshift) % HH;
        const int x = (wx * 5 + i % 5 + gshift) % WW;
        const int base = y * WW + x;
        float q[4], k[4];
        float qsq = 0.f, ksq = 0.f;
#pragma unroll
        for (int d = 0; d < 4; ++d) {
            q[d] = fq[(h * 4 + d) * PP + base];
            k[d] = kv[(h * 4 + d) * PP + base];
            vs[h][i][d] = kv[((8 + h) * 4 + d) * PP + base];
            qsq += q[d] * q[d];
            ksq += k[d] * k[d];
        }
        const float scale = __expf(fminf(lsc[h], LOG_MAX_C));
        const float qs = scale * LOG2E;
        negM2 = -qs;
        const float qinv = qs / fmaxf(sqrtf(qsq), 1e-12f);
        const float kinv = 1.0f / fmaxf(sqrtf(ksq), 1e-12f);
#pragma unroll
        for (int d = 0; d < 4; ++d) {
            qn[d] = q[d] * qinv;
            ks[h][i][d] = k[d] * kinv;
        }
        oy = (wy * 5 + i / 5 + sshift) % HH;
        ox = (wx * 5 + i % 5 + sshift) % WW;
    }
    __syncthreads();
    if (t < 200) {
        float l = 0.f, acc[4] = {0, 0, 0, 0};
#pragma unroll
        for (int j = 0; j < 25; ++j) {
            const float s = fmaf(qn[0], ks[h][j][0],
                            fmaf(qn[1], ks[h][j][1],
                            fmaf(qn[2], ks[h][j][2],
                            fmaf(qn[3], ks[h][j][3], negM2))));
            const float p = EXP2F(s);
            l += p;
#pragma unroll
            for (int d = 0; d < 4; ++d) acc[d] = fmaf(p, vs[h][j][d], acc[d]);
        }
        const float linv = 1.0f / l;
        union { __bf16 h4[4]; uint2 u; } o;
#pragma unroll
        for (int d = 0; d < 4; ++d) o.h4[d] = (__bf16)(acc[d] * linv);
        *(uint2*)(ys + (((size_t)(oy + 1) * 3 + icb) * PW + ox + 1) * 32 + h * 4) = o.u;
    }
}

// ---------------------------------------------------------------------------
// Axial row attention (over w). One block per (row y, head h); t = query x.
// Row-major reads are naturally coalesced — no swizzle needed.
// ---------------------------------------------------------------------------
__global__ __launch_bounds__(256) void axial_row_kernel(
    const float* __restrict__ fq, const float* __restrict__ kv,
    const float* __restrict__ lsc, float* __restrict__ v1)
{
    __shared__ float ks[240][4];
    __shared__ float vs[240][4];
    const int t = threadIdx.x;
    const int y = blockIdx.x, h = blockIdx.y;

    float q[4] = {0, 0, 0, 0};
    float negM2 = 0.f;
    if (t < 240) {
        float k[4];
        float ksq = 0.f, qsq = 0.f;
#pragma unroll
        for (int d = 0; d < 4; ++d) {
            k[d] = kv[(h * 4 + d) * PP + y * WW + t];
            vs[t][d] = kv[((8 + h) * 4 + d) * PP + y * WW + t];
            q[d] = fq[(h * 4 + d) * PP + y * WW + t];
            ksq += k[d] * k[d];
            qsq += q[d] * q[d];
        }
        const float kinv = 1.0f / fmaxf(sqrtf(ksq), 1e-12f);
#pragma unroll
        for (int d = 0; d < 4; ++d) ks[t][d] = k[d] * kinv;
        const float scale = __expf(fminf(lsc[h], LOG_MAX_C));
        const float qs = scale * LOG2E;
        negM2 = -qs;
        const float qinv = qs / fmaxf(sqrtf(qsq), 1e-12f);
#pragma unroll
        for (int d = 0; d < 4; ++d) q[d] *= qinv;
    }
    __syncthreads();
    if (t < 240) {
        float l = 0.f, acc[4] = {0, 0, 0, 0};
        for (int j = 0; j < 240; ++j) {
            const float s = fmaf(q[0], ks[j][0],
                            fmaf(q[1], ks[j][1],
                            fmaf(q[2], ks[j][2],
                            fmaf(q[3], ks[j][3], negM2))));
            const float p = EXP2F(s);
            l += p;
#pragma unroll
            for (int d = 0; d < 4; ++d) acc[d] = fmaf(p, vs[j][d], acc[d]);
        }
        const float linv = 1.0f / l;
#pragma unroll
        for (int d = 0; d < 4; ++d)
            v1[(h * 4 + d) * PP + y * WW + t] = acc[d] * linv;
    }
}

// ---------------------------------------------------------------------------
// Axial column attention (over h). v2: 1D grid (1920) with XCD swizzle —
// the 16 blocks covering one 16-column 64B-line group go to one XCD:
// i=bid/120, g=bid%120, h=g%8, x=(g/8)*16+i; 120%8==0 so bid%8==g%8.
// Per-XCD resident line set ~2.8 MB < 4 MB L2, so each line is fetched
// once per XCD instead of ~8x (r7 FETCH=93 MB vs 22 MB logical).
// ---------------------------------------------------------------------------
__global__ __launch_bounds__(256) void axial_col_kernel(
    const float* __restrict__ fq, const float* __restrict__ kv,
    const float* __restrict__ v1, const float* __restrict__ lsc,
    __bf16* __restrict__ ys)
{
    __shared__ float ks[240][4];
    __shared__ float vs[240][4];
    const int bid = blockIdx.x;
    const int wi  = bid / 120;
    const int g   = bid % 120;
    const int h   = g % 8;
    const int x   = (g / 8) * 16 + wi;
    const int t = threadIdx.x;

    float q[4] = {0, 0, 0, 0};
    float negM2 = 0.f;
    if (t < 240) {
        float k[4];
        float ksq = 0.f, qsq = 0.f;
#pragma unroll
        for (int d = 0; d < 4; ++d) {
            k[d] = kv[(h * 4 + d) * PP + t * WW + x];
            vs[t][d] = v1[(h * 4 + d) * PP + t * WW + x];
            q[d] = fq[(h * 4 + d) * PP + t * WW + x];
            ksq += k[d] * k[d];
            qsq += q[d] * q[d];
        }
        const float kinv = 1.0f / fmaxf(sqrtf(ksq), 1e-12f);
#pragma unroll
        for (int d = 0; d < 4; ++d) ks[t][d] = k[d] * kinv;
        const float scale = __expf(fminf(lsc[h], LOG_MAX_C));
        const float qs = scale * LOG2E;
        negM2 = -qs;
        const float qinv = qs / fmaxf(sqrtf(qsq), 1e-12f);
#pragma unroll
        for (int d = 0; d < 4; ++d) q[d] *= qinv;
    }
    __syncthreads();
    if (t < 240) {
        float l = 0.f, acc[4] = {0, 0, 0, 0};
        for (int j = 0; j < 240; ++j) {
            const float s = fmaf(q[0], ks[j][0],
                            fmaf(q[1], ks[j][1],
                            fmaf(q[2], ks[j][2],
                            fmaf(q[3], ks[j][3], negM2))));
            const float p = EXP2F(s);
            l += p;
#pragma unroll
            for (int d = 0; d < 4; ++d) acc[d] = fmaf(p, vs[j][d], acc[d]);
        }
        const float linv = 1.0f / l;
        union { __bf16 h4[4]; uint2 u; } o;
#pragma unroll
        for (int d = 0; d < 4; ++d) o.h4[d] = (__bf16)(acc[d] * linv);
        *(uint2*)(ys + (((size_t)(t + 1) * 3 + 2) * PW + x + 1) * 32 + h * 4) = o.u;
    }
}

// ---------------------------------------------------------------------------
// Pipeline: wt_frag x3; x -> xs; conv_in/conv_f; zero ys border (ys aliases
// xs); attention -> ys (fragment layout); conv_out -> d_out.
// ---------------------------------------------------------------------------
extern "C" void kernel_launch(void* const* d_in, const int* in_sizes, int n_in,
                              void* d_out, int out_size, void* d_ws, size_t ws_size,
                              hipStream_t stream)
{
    const float* x     = (const float*)d_in[0];
    const float* w_in  = (const float*)d_in[1];
    const float* b_in  = (const float*)d_in[2];
    const float* w_f   = (const float*)d_in[3];
    const float* b_f   = (const float*)d_in[4];
    const float* w_out = (const float*)d_in[5];
    const float* b_out = (const float*)d_in[6];
    const float* lsc   = (const float*)d_in[7];
    const float* lrlsc = (const float*)d_in[8];
    float* out = (float*)d_out;

    float* ws = (float*)d_ws;
    float* xp = ws;                    // 192*PP f32
    float* fp = xp + 192 * PP;         //  96*PP f32
    float* v1 = fp + 96 * PP;          //  32*PP f32
    __bf16* xs     = (__bf16*)(v1 + 32 * PP);             // 242*3*242*32 bf16
    __bf16* wtf_in = xs + (size_t)PW * 3 * PW * 32;       // 9*12*3*512
    __bf16* wtf_f  = wtf_in + 9 * 12 * 3 * 512;           // 9*6*3*512
    __bf16* wtf_o  = wtf_f + 9 * 6 * 3 * 512;             // 9*6*3*512
    __bf16* ys     = xs;               // alias: xs dead after conv_in/conv_f

    wt_frag<<<(9 * 12 * 3 * 64 + 255) / 256, 256, 0, stream>>>(w_in, wtf_in, 192);
    wt_frag<<<(9 * 6 * 3 * 64 + 255) / 256, 256, 0, stream>>>(w_f, wtf_f, 96);
    wt_frag<<<(9 * 6 * 3 * 64 + 255) / 256, 256, 0, stream>>>(w_out, wtf_o, 96);
    to_xs_pad<<<(PW * PW + 255) / 256, 256, 0, stream>>>(x, xs);

    conv3x3_mfma<192, 4><<<1368, 256, 0, stream>>>(xs, wtf_in, b_in, xp);
    conv3x3_mfma<96, 2><<<1368, 256, 0, stream>>>(xs, wtf_f, b_f, fp);

    zero_border_xs<<<(4 * PW + 255) / 256, 256, 0, stream>>>(ys);

    win_attn_kernel<<<2304, 256, 0, stream>>>(fp, xp, lsc, ys, 0, 0, 0);
    win_attn_kernel<<<2304, 256, 0, stream>>>(fp + 32 * PP, xp + 64 * PP,
                                              lsc, ys, 3, 2, 1);
    axial_row_kernel<<<dim3(240, 8), 256, 0, stream>>>(fp + 64 * PP, xp + 128 * PP,
                                                       lrlsc, v1);
    axial_col_kernel<<<1920, 256, 0, stream>>>(fp + 64 * PP, xp + 128 * PP,
                                               v1, lrlsc, ys);

    conv3x3_mfma<96, 2><<<1368, 256, 0, stream>>>(ys, wtf_o, b_out, out);
}